// Round 1
// baseline (422.879 us; speedup 1.0000x reference)
//
#include <hip/hip_runtime.h>

// ResLSTM: B=4096, T=512, H=32. One wave64 per batch element.
// Lane l computes gate rows l and l+64:
//   lanes 0..31:  row l = i,  row l+64 = g
//   lanes 32..63: row l = f,  row l+64 = o
//
// R4 win: h-broadcast via LDS (same-address ds_read_b128), 407 -> 330 us.
// R5: waves_per_eu(4,4) clamp -> 330 -> 316, VGPR 52 -> 60.
// R7: volatile weight pins (weights must stay VGPR-resident), 357 baseline.
// R8 (this round): LDS-pipe was the bottleneck theory. 9 LDS ops/wave/step
// (8x ds_read_b128 broadcast + 1x ds_write) x 16 waves/CU on ONE shared LDS
// pipe ~ 1000-2000 cy/CU/step == the observed 1600 cy/step budget, while
// VALUBusy sat at 72%. Replace the LDS h-broadcast with 32x v_readlane into
// SGPRs (h[j] is uniform; v_fma_f32 takes one SGPR operand, same trick as
// xt). Zero LDS storage, zero LDS ops in the loop except the two
// __shfl_xor(.,32) exchanges (kept for bitwise-identical numerics).
// Accumulation order and gate math are bit-identical to R7.

static constexpr int T_LEN = 512;
static constexpr int H = 32;

__device__ __forceinline__ float rl_c(float v, int l) {
    return __int_as_float(__builtin_amdgcn_readlane(__float_as_int(v), l));
}

// exp2-based sigmoid: sigmoid(x) = rcp(1 + exp2(x * -log2(e)))
__device__ __forceinline__ float sig_e2(float x_times_nlog2e) {
    return __builtin_amdgcn_rcpf(1.0f + __builtin_amdgcn_exp2f(x_times_nlog2e));
}

__global__ void
__attribute__((amdgpu_flat_work_group_size(256, 256), amdgpu_waves_per_eu(4, 4)))
reslstm_kernel(const float* __restrict__ x,
               const float* __restrict__ W_ih,
               const float* __restrict__ W_hh,
               const float* __restrict__ b_ih,
               const float* __restrict__ b_hh,
               const float* __restrict__ W_fc,
               const float* __restrict__ b_fc,
               float* __restrict__ out, int B)
{
    const int lane = threadIdx.x & 63;
    const int wv   = threadIdx.x >> 6;
    const int b    = (blockIdx.x << 2) + wv;
    if (b >= B) return;                       // wave-uniform guard

    const int r0 = lane;                      // i | f
    const int r1 = lane + 64;                 // g | o

    // W_hh rows for this lane -> 64 VGPR-resident floats (loaded as float4).
    const float4* pa = reinterpret_cast<const float4*>(W_hh + r0 * H);
    const float4* pb = reinterpret_cast<const float4*>(W_hh + r1 * H);
    float wa[32], wq[32];
    #pragma unroll
    for (int k = 0; k < 8; ++k) {
        const float4 ta = pa[k], tq = pb[k];
        wa[4*k+0] = ta.x; wa[4*k+1] = ta.y; wa[4*k+2] = ta.z; wa[4*k+3] = ta.w;
        wq[4*k+0] = tq.x; wq[4*k+1] = tq.y; wq[4*k+2] = tq.z; wq[4*k+3] = tq.w;
    }

    float wih0  = W_ih[r0];
    float wih1  = W_ih[r1];
    float bias0 = b_ih[r0] + b_hh[r0];
    float bias1 = b_ih[r1] + b_hh[r1];

    // Branchless tanh-vs-sigmoid for the r1 gate: tanh(x)=2*sigmoid(2x)-1.
    const bool lo = (lane < 32);
    constexpr float NL2E = -1.4426950408889634f;
    float e1 = lo ? 2.0f * NL2E : NL2E;
    float s1 = lo ? 2.0f : 1.0f;
    float t1 = lo ? -1.0f : 0.0f;

    // h(t-1) broadcast lives in SGPRs: hs[j] = readlane(h, j). Uniform values,
    // consumed directly as the one-SGPR operand of each MAC v_fma_f32.
    float hs[32];
    #pragma unroll
    for (int j = 0; j < 32; ++j) hs[j] = 0.0f;   // h0 = 0
    float h = 0.0f, c = 0.0f;

    const float* xrow = x + (size_t)b * T_LEN;

// Volatile pins: executed once per iteration, outputs feed next iteration.
// Reloading these from memory is illegal -> all 64 weight floats + 7 loop
// scalars MUST stay VGPR-resident. (hs[] is deliberately NOT pinned: those
// are uniform/SGPR values and a "+v" pin would force them into VGPRs.)
#define PIN16(P)                                                              \
    asm volatile("" : "+v"((P)[0]),  "+v"((P)[1]),  "+v"((P)[2]),  "+v"((P)[3]), \
                      "+v"((P)[4]),  "+v"((P)[5]),  "+v"((P)[6]),  "+v"((P)[7]), \
                      "+v"((P)[8]),  "+v"((P)[9]),  "+v"((P)[10]), "+v"((P)[11]),\
                      "+v"((P)[12]), "+v"((P)[13]), "+v"((P)[14]), "+v"((P)[15]))
#define PINALL()                                                              \
    PIN16(wa); PIN16(wa + 16); PIN16(wq); PIN16(wq + 16);                     \
    asm volatile("" : "+v"(wih0), "+v"(wih1), "+v"(bias0), "+v"(bias1),       \
                      "+v"(e1), "+v"(s1), "+v"(t1))

    for (int tc = 0; tc < T_LEN / 64; ++tc) {
        const float xv = xrow[(tc << 6) + lane];   // coalesced 64-float chunk
        #pragma unroll 4
        for (int tt = 0; tt < 64; ++tt) {
            PINALL();                              // force weight residency
            const float xt = rl_c(xv, tt);         // x[b][t], wave-uniform
            float aA  = __builtin_fmaf(xt, wih0, bias0);
            float aB  = __builtin_fmaf(xt, wih1, bias1);
            float aA2 = 0.0f, aB2 = 0.0f;
            // Same accumulation order as R7 (even j -> aA, odd j -> aA2):
            // bitwise-identical gate pre-activations.
            #pragma unroll
            for (int j = 0; j < 32; j += 2) {
                aA  = __builtin_fmaf(wa[j],   hs[j],   aA);
                aB  = __builtin_fmaf(wq[j],   hs[j],   aB);
                aA2 = __builtin_fmaf(wa[j+1], hs[j+1], aA2);
                aB2 = __builtin_fmaf(wq[j+1], hs[j+1], aB2);
            }
            aA += aA2; aB += aB2;
            const float g0 = sig_e2(aA * NL2E);                       // i | f
            const float g1 = __builtin_fmaf(s1, sig_e2(aB * e1), t1); // g | o
            const float fo = __shfl_xor(g0, 32);   // lanes<32 get f[j]
            const float og = __shfl_xor(g1, 32);   // lanes<32 get o[j]
            // lanes>=32 carry bounded garbage c,h; their h is never
            // readlane'd (broadcast sources lanes 0..31 only).
            c = __builtin_fmaf(fo, c, g0 * g1);                       // f*c+i*g
            const float th = __builtin_fmaf(2.0f, sig_e2(c * (2.0f * NL2E)), -1.0f);
            h = og * th;                                              // o*tanh(c)
            // publish h for next step: lane j -> SGPR hs[j] (VALU pipe,
            // no LDS, no lgkmcnt on the recurrence critical path)
            #pragma unroll
            for (int j = 0; j < 32; ++j) hs[j] = rl_c(h, j);
        }
    }
#undef PINALL
#undef PIN16

    // out[b] = sum_j h[j]*W_fc[j] + b_fc  (butterfly reduce over the wave)
    float val = lo ? h * W_fc[lane & (H - 1)] : 0.0f;
    #pragma unroll
    for (int off = 32; off >= 1; off >>= 1)
        val += __shfl_xor(val, off);
    if (lane == 0) out[b] = val + b_fc[0];
}

extern "C" void kernel_launch(void* const* d_in, const int* in_sizes, int n_in,
                              void* d_out, int out_size, void* d_ws, size_t ws_size,
                              hipStream_t stream) {
    const float* x    = (const float*)d_in[0];
    const float* W_ih = (const float*)d_in[1];
    const float* W_hh = (const float*)d_in[2];
    const float* b_ih = (const float*)d_in[3];
    const float* b_hh = (const float*)d_in[4];
    const float* W_fc = (const float*)d_in[5];
    const float* b_fc = (const float*)d_in[6];
    float* out = (float*)d_out;
    const int B = in_sizes[0] / T_LEN;        // 4096
    dim3 block(256);                          // 4 waves = 4 batch elements
    dim3 grid((B + 3) / 4);                   // 1024 blocks -> 4 waves/SIMD
    reslstm_kernel<<<grid, block, 0, stream>>>(x, W_ih, W_hh, b_ih, b_hh,
                                               W_fc, b_fc, out, B);
}